// Round 9
// baseline (1146.963 us; speedup 1.0000x reference)
//
#include <hip/hip_runtime.h>
#include <math.h>

#define F_OUT     32
#define GRID_DIM  32
#define NUM_VOX   (GRID_DIM * GRID_DIM * GRID_DIM)

#define NPB   64             // nodes per bucket; bucket = dst >> 6
#define NBKT  1024           // bucket table size (Nn <= 65536)
#define SEB   2048           // edges per sort block
#define SCS   132            // sC row stride (floats): 528 B, 16B-aligned
#define DEGS  125            // degree slot within sC row
#define ECAP  3072           // owner work-list capacity (mean 1024, +64 sigma)

// ---------- monotonic float<->uint encoding for atomicMax on signed floats ----
__device__ __forceinline__ unsigned int enc_f32(float f) {
    unsigned int u = __float_as_uint(f);
    return (u & 0x80000000u) ? ~u : (u | 0x80000000u);
}
__device__ __forceinline__ float dec_f32(unsigned int e) {
    return (e & 0x80000000u) ? __uint_as_float(e ^ 0x80000000u)
                             : __uint_as_float(~e);
}

// ---------- K1: block-local counting sort, payload built in registers --------
__global__ __launch_bounds__(512, 4) void sort_kernel(
    const int*   __restrict__ src,
    const int*   __restrict__ dst,
    const float* __restrict__ x,
    const float* __restrict__ pseudo,
    float4* __restrict__ payload,          // [nSB * SEB]
    unsigned int* __restrict__ off_tab,    // [nSB][NBKT] packed: local_start | cnt<<16
    int E)
{
    __shared__ unsigned int sHist[NBKT];   // hist -> cursor (4 KB)
    __shared__ unsigned int sStart[NBKT];  // exclusive starts (4 KB)
    __shared__ unsigned int sWTot[8];      // per-wave scan totals
    __shared__ __align__(16) float4 sPay[SEB];   // staged payload (32 KB)

    const int t    = threadIdx.x;
    const int lane = t & 63;
    const int wv   = t >> 6;
    const int e0   = blockIdx.x * SEB;

    for (int i = t; i < NBKT; i += 512) sHist[i] = 0;
    __syncthreads();

    // pass A: coalesced loads, payload in registers, histogram.
    // validity = index range (e < E); dst==65535 is a legal node id, no sentinel.
    unsigned short dloc[4];
    float4 pay[4];
    #pragma unroll
    for (int i = 0; i < 4; ++i) {
        int e = e0 + i * 512 + t;
        if (e < E) {
            int d = dst[e];
            int s = src[e];
            float p0 = pseudo[3 * e], p1 = pseudo[3 * e + 1], p2 = pseudo[3 * e + 2];
            float xj = x[s];
            unsigned int q2 = (unsigned int)(p2 * 65535.0f + 0.5f) & 0xFFFFu;
            unsigned int w  = q2 | ((unsigned int)(d & 63) << 16);
            dloc[i] = (unsigned short)d;
            pay[i]  = make_float4(p0, p1, xj, __uint_as_float(w));
            atomicAdd(&sHist[d >> 6], 1u);
        } else dloc[i] = 0;
    }
    __syncthreads();

    // exclusive scan of 1024 buckets: pair-sum + wave shfl-scan + cross-wave (2 barriers)
    unsigned int a0 = sHist[2 * t], a1 = sHist[2 * t + 1];
    unsigned int pairSum = a0 + a1;
    unsigned int incl = pairSum;
    #pragma unroll
    for (int d = 1; d < 64; d <<= 1) {
        unsigned int v = __shfl_up(incl, d, 64);
        if (lane >= d) incl += v;
    }
    if (lane == 63) sWTot[wv] = incl;
    __syncthreads();
    unsigned int wofs = 0, total = 0;
    #pragma unroll
    for (int w = 0; w < 8; ++w) {
        unsigned int v = sWTot[w];
        if (w < wv) wofs += v;
        total += v;
    }
    unsigned int ex = wofs + incl - pairSum;
    sStart[2 * t]     = ex;
    sStart[2 * t + 1] = ex + a0;
    sHist[2 * t]      = ex;            // cursor copy
    sHist[2 * t + 1]  = ex + a0;
    __syncthreads();

    // pass B: place payloads into LDS by bucket (same validity rule)
    #pragma unroll
    for (int i = 0; i < 4; ++i) {
        int e = e0 + i * 512 + t;
        if (e < E) {
            unsigned int slot = atomicAdd(&sHist[dloc[i] >> 6], 1u);
            sPay[slot] = pay[i];
        }
    }
    __syncthreads();

    // streamout: coalesced 16B stores to this block's private slab
    for (unsigned int i = t; i < total; i += 512)
        payload[(size_t)e0 + i] = sPay[i];

    // packed offset table, coalesced row write
    for (int b = t; b < NBKT; b += 512) {
        unsigned int s = sStart[b];
        unsigned int nxt = (b < NBKT - 1) ? sStart[b + 1] : total;
        off_tab[(size_t)blockIdx.x * NBKT + b] = s | ((nxt - s) << 16);
    }
}

// ---------- per-edge accumulation: 9 scattered LDS atomics -------------------
__device__ __forceinline__ void process_edge(float4 r, float* sC)
{
    float xj = r.z;
    unsigned int w = __float_as_uint(r.w);
    int   rel = (int)((w >> 16) & 63u);
    float p2  = (float)(w & 0xFFFFu) * (1.0f / 65535.0f);

    float v0 = r.x * 4.0f, v1 = r.y * 4.0f, v2 = p2 * 4.0f;
    float i0 = fminf(fmaxf(floorf(v0), 0.0f), 3.0f);
    float i1 = fminf(fmaxf(floorf(v1), 0.0f), 3.0f);
    float i2 = fminf(fmaxf(floorf(v2), 0.0f), 3.0f);
    float f0 = v0 - i0, f1 = v1 - i1, f2 = v2 - i2;
    float g0 = 1.0f - f0, g1 = 1.0f - f1, g2 = 1.0f - f2;
    int k = (int)i0 + 5 * (int)i1 + 25 * (int)i2;        // 0..93

    float w00 = g0 * g1, w10 = f0 * g1, w01 = g0 * f1, w11 = f0 * f1;
    float a2 = xj * g2, b2 = xj * f2;
    float* row = sC + rel * SCS;
    atomicAdd(row + k +  0, w00 * a2);
    atomicAdd(row + k +  1, w10 * a2);
    atomicAdd(row + k +  5, w01 * a2);
    atomicAdd(row + k +  6, w11 * a2);
    atomicAdd(row + k + 25, w00 * b2);
    atomicAdd(row + k + 26, w10 * b2);
    atomicAdd(row + k + 30, w01 * b2);
    atomicAdd(row + k + 31, w11 * b2);
    atomicAdd(row + DEGS, 1.0f);                         // degree
}

// ---------- K2: owner block — work list, LDS accumulate, GEMM, epilogue ------
__global__ __launch_bounds__(512, 4) void owner_kernel(
    const float4* __restrict__ payload,
    const unsigned int* __restrict__ off_tab,   // [nSB][NBKT] packed
    const float* __restrict__ W,        // [125,32]
    const float* __restrict__ x,        // [N,1]
    const float* __restrict__ W_root,   // [32]
    const float* __restrict__ bias,     // [32]
    const float* __restrict__ pos,      // [N,3]
    unsigned int* __restrict__ pooled,  // [NUM_VOX,32] encoded
    int Nn, int nSB)
{
    __shared__ __align__(16) float sC[NPB * SCS];   // 33792 B
    __shared__ unsigned int sEdge[ECAP];            // 12288 B
    __shared__ unsigned int sNe;

    const int t = threadIdx.x;
    const int b = blockIdx.x;
    const int lane = t & 63;

    // zero sC
    for (int i = t; i < NPB * SCS / 4; i += 512)
        *(float4*)&sC[i * 4] = make_float4(0.f, 0.f, 0.f, 0.f);
    if (t == 0) sNe = 0;

    // my fragment (sort block t's slice of bucket b)
    unsigned int cnt = 0, start_g = 0;
    if (t < nSB) {
        unsigned int packed = off_tab[(size_t)t * NBKT + b];
        start_g = (unsigned int)t * SEB + (packed & 0xFFFFu);
        cnt = packed >> 16;
    }
    __syncthreads();

    // wave-level exclusive prefix of cnt -> compact work list offsets
    unsigned int incl = cnt;
    #pragma unroll
    for (int d = 1; d < 64; d <<= 1) {
        unsigned int v = __shfl_up(incl, d, 64);
        if (lane >= d) incl += v;
    }
    unsigned int wtot = __shfl(incl, 63, 64);
    unsigned int wbase = 0;
    if (lane == 63 && wtot > 0) wbase = atomicAdd(&sNe, wtot);
    wbase = __shfl(wbase, 63, 64);
    unsigned int off = wbase + incl - cnt;

    for (unsigned int j = 0; j < cnt; ++j) {
        unsigned int p = off + j;
        if (p < ECAP) sEdge[p] = start_g + j;
        else process_edge(payload[start_g + j], sC);   // statistically unreachable
    }
    __syncthreads();

    // edge phase: 2 edges in flight per thread (MLP)
    int ne = (int)sNe; if (ne > ECAP) ne = ECAP;
    for (int i = t; i < ne; i += 1024) {
        unsigned int ei = sEdge[i];
        int j = i + 512;
        bool hj = (j < ne);
        unsigned int ej = hj ? sEdge[j] : ei;
        float4 r0 = payload[ei];
        float4 r1 = payload[ej];
        process_edge(r0, sC);
        if (hj) process_edge(r1, sC);
    }
    __syncthreads();

    // dense GEMM: [64 x 125] @ [125 x 32], 4 channels/thread,
    // depth-1 software pipeline, fully unrolled
    const int node = t & 63;
    const int cg   = t >> 6;                 // wave-uniform channel group 0..7
    const float4* crow4 = (const float4*)(sC + node * SCS);
    const float4* WB    = (const float4*)W;  // W[k][cg*4..] = WB[k*8+cg]
    float4 acc = make_float4(0.f, 0.f, 0.f, 0.f);

    float4 r  = crow4[0];
    float4 wa = WB[0 * 8 + cg], wb = WB[1 * 8 + cg];
    float4 wc = WB[2 * 8 + cg], wd = WB[3 * 8 + cg];
    #pragma unroll
    for (int k4 = 0; k4 < 31; ++k4) {
        float4 rn = r, na = wa, nb2 = wb, nc = wc, nd = wd;
        if (k4 < 30) {
            rn = crow4[k4 + 1];
            int kb = 4 * (k4 + 1);
            na  = WB[(kb + 0) * 8 + cg];
            nb2 = WB[(kb + 1) * 8 + cg];
            nc  = WB[(kb + 2) * 8 + cg];
            nd  = WB[(kb + 3) * 8 + cg];
        }
        acc.x += r.x * wa.x + r.y * wb.x + r.z * wc.x + r.w * wd.x;
        acc.y += r.x * wa.y + r.y * wb.y + r.z * wc.y + r.w * wd.y;
        acc.z += r.x * wa.z + r.y * wb.z + r.z * wc.z + r.w * wd.z;
        acc.w += r.x * wa.w + r.y * wb.w + r.z * wc.w + r.w * wd.w;
        r = rn; wa = na; wb = nb2; wc = nc; wd = nd;
    }
    {   // k = 124
        float rr = sC[node * SCS + 124];
        float4 wl = WB[124 * 8 + cg];
        acc.x += rr * wl.x; acc.y += rr * wl.y;
        acc.z += rr * wl.z; acc.w += rr * wl.w;
    }

    // epilogue straight from registers (no LDS round-trip, no extra barrier)
    float dg = fmaxf(sC[node * SCS + DEGS], 1.0f);
    int   n  = b * NPB + node;
    if (n < Nn) {
        float  xn = x[n];
        float4 wr = *(const float4*)(W_root + cg * 4);
        float4 bs = *(const float4*)(bias + cg * 4);
        float h0 = acc.x / dg + xn * wr.x + bs.x; h0 = h0 > 0.f ? h0 : expm1f(h0);
        float h1 = acc.y / dg + xn * wr.y + bs.y; h1 = h1 > 0.f ? h1 : expm1f(h1);
        float h2 = acc.z / dg + xn * wr.z + bs.z; h2 = h2 > 0.f ? h2 : expm1f(h2);
        float h3 = acc.w / dg + xn * wr.w + bs.w; h3 = h3 > 0.f ? h3 : expm1f(h3);

        int vx = min(max((int)floorf(pos[3 * n + 0] * (float)GRID_DIM), 0), GRID_DIM - 1);
        int vy = min(max((int)floorf(pos[3 * n + 1] * (float)GRID_DIM), 0), GRID_DIM - 1);
        int vz = min(max((int)floorf(pos[3 * n + 2] * (float)GRID_DIM), 0), GRID_DIM - 1);
        int vidx = vx + GRID_DIM * vy + GRID_DIM * GRID_DIM * vz;
        unsigned int* pv = pooled + (size_t)vidx * F_OUT + cg * 4;
        atomicMax(pv + 0, enc_f32(h0));
        atomicMax(pv + 1, enc_f32(h1));
        atomicMax(pv + 2, enc_f32(h2));
        atomicMax(pv + 3, enc_f32(h3));
    }
}

// ---------- K3: decode, empty voxels -> 0 ------------------------------------
__global__ __launch_bounds__(256) void finalize_kernel(
    const unsigned int* __restrict__ pooled,
    float* __restrict__ out, int M)
{
    int i = blockIdx.x * blockDim.x + threadIdx.x;
    if (i >= M) return;
    unsigned int u = pooled[i];
    out[i] = (u == 0u) ? 0.0f : dec_f32(u);
}

// ============================ launcher =======================================
extern "C" void kernel_launch(void* const* d_in, const int* in_sizes, int n_in,
                              void* d_out, int out_size, void* d_ws, size_t ws_size,
                              hipStream_t stream) {
    const float* x       = (const float*)d_in[0];
    const int*   ei      = (const int*)  d_in[1];
    const float* pseudo  = (const float*)d_in[2];
    const float* pos     = (const float*)d_in[3];
    const float* W       = (const float*)d_in[4];
    const float* W_root  = (const float*)d_in[5];
    const float* bias    = (const float*)d_in[6];
    float* out = (float*)d_out;

    const int E   = in_sizes[1] / 2;
    const int Nn  = in_sizes[0];                  // F_IN == 1, Nn <= 65536
    const int nSB = (E + SEB - 1) / SEB;          // sort blocks (512 here)
    const int nb  = (Nn + NPB - 1) / NPB;         // owner buckets (1024 here)

    // workspace: [pooled 4MB][off_tab nSB*NBKT*4][payload nSB*SEB*16]
    const size_t pooled_b = (size_t)NUM_VOX * F_OUT * 4;
    const size_t off_b    = (size_t)nSB * NBKT * 4;
    unsigned int* pooled  = (unsigned int*)d_ws;
    unsigned int* off_tab = (unsigned int*)((char*)d_ws + pooled_b);
    float4*       payload = (float4*)((char*)d_ws + pooled_b + ((off_b + 15) & ~(size_t)15));

    hipMemsetAsync(pooled, 0, pooled_b, stream);

    sort_kernel<<<nSB, 512, 0, stream>>>(ei, ei + E, x, pseudo, payload, off_tab, E);
    owner_kernel<<<nb, 512, 0, stream>>>(payload, off_tab, W, x, W_root, bias, pos,
                                         pooled, Nn, nSB);

    const int M = (out_size < NUM_VOX * F_OUT) ? out_size : NUM_VOX * F_OUT;
    finalize_kernel<<<(M + 255) / 256, 256, 0, stream>>>(pooled, out, M);
}

// Round 10
// 175.088 us; speedup vs baseline: 6.5508x; 6.5508x over previous
//
#include <hip/hip_runtime.h>
#include <math.h>

#define F_OUT     32
#define GRID_DIM  32
#define NUM_VOX   (GRID_DIM * GRID_DIM * GRID_DIM)

#define NPB   64             // nodes per bucket; bucket = dst >> 6
#define NBKT  1024           // bucket table size (Nn <= 65536)
#define SEB   2048           // edges per sort block
#define SCS   132            // sC row stride (floats): 528 B, 16B-aligned
#define DEGS  125            // degree slot within sC row
#define ECAP  3072           // owner work-list capacity (mean 1024, +64 sigma)

// ---------- monotonic float<->uint encoding for atomicMax on signed floats ----
__device__ __forceinline__ unsigned int enc_f32(float f) {
    unsigned int u = __float_as_uint(f);
    return (u & 0x80000000u) ? ~u : (u | 0x80000000u);
}
__device__ __forceinline__ float dec_f32(unsigned int e) {
    return (e & 0x80000000u) ? __uint_as_float(e ^ 0x80000000u)
                             : __uint_as_float(~e);
}

// ---------- K1: block-local counting sort, payload built in registers --------
__global__ __launch_bounds__(512, 4) void sort_kernel(
    const int*   __restrict__ src,
    const int*   __restrict__ dst,
    const float* __restrict__ x,
    const float* __restrict__ pseudo,
    float4* __restrict__ payload,          // [nSB * SEB]
    unsigned int* __restrict__ off_tab,    // [nSB][NBKT] packed: local_start | cnt<<16
    int E)
{
    __shared__ unsigned int sHist[NBKT];   // hist -> cursor (4 KB)
    __shared__ unsigned int sStart[NBKT];  // exclusive starts (4 KB)
    __shared__ unsigned int sWTot[8];      // per-wave scan totals
    __shared__ __align__(16) float4 sPay[SEB];   // staged payload (32 KB)

    const int t    = threadIdx.x;
    const int lane = t & 63;
    const int wv   = t >> 6;
    const int e0   = blockIdx.x * SEB;

    for (int i = t; i < NBKT; i += 512) sHist[i] = 0;
    __syncthreads();

    // pass A: coalesced loads, payload in registers, histogram.
    // validity = index range (e < E); dst==65535 is a legal node id, no sentinel.
    unsigned short dloc[4];
    float4 pay[4];
    #pragma unroll
    for (int i = 0; i < 4; ++i) {
        int e = e0 + i * 512 + t;
        if (e < E) {
            int d = dst[e];
            int s = src[e];
            float p0 = pseudo[3 * e], p1 = pseudo[3 * e + 1], p2 = pseudo[3 * e + 2];
            float xj = x[s];
            unsigned int q2 = (unsigned int)(p2 * 65535.0f + 0.5f) & 0xFFFFu;
            unsigned int w  = q2 | ((unsigned int)(d & 63) << 16);
            dloc[i] = (unsigned short)d;
            pay[i]  = make_float4(p0, p1, xj, __uint_as_float(w));
            atomicAdd(&sHist[d >> 6], 1u);
        } else dloc[i] = 0;
    }
    __syncthreads();

    // exclusive scan of 1024 buckets: pair-sum + wave shfl-scan + cross-wave (2 barriers)
    unsigned int a0 = sHist[2 * t], a1 = sHist[2 * t + 1];
    unsigned int pairSum = a0 + a1;
    unsigned int incl = pairSum;
    #pragma unroll
    for (int d = 1; d < 64; d <<= 1) {
        unsigned int v = __shfl_up(incl, d, 64);
        if (lane >= d) incl += v;
    }
    if (lane == 63) sWTot[wv] = incl;
    __syncthreads();
    unsigned int wofs = 0, total = 0;
    #pragma unroll
    for (int w = 0; w < 8; ++w) {
        unsigned int v = sWTot[w];
        if (w < wv) wofs += v;
        total += v;
    }
    unsigned int ex = wofs + incl - pairSum;
    sStart[2 * t]     = ex;
    sStart[2 * t + 1] = ex + a0;
    sHist[2 * t]      = ex;            // cursor copy
    sHist[2 * t + 1]  = ex + a0;
    __syncthreads();

    // pass B: place payloads into LDS by bucket (same validity rule)
    #pragma unroll
    for (int i = 0; i < 4; ++i) {
        int e = e0 + i * 512 + t;
        if (e < E) {
            unsigned int slot = atomicAdd(&sHist[dloc[i] >> 6], 1u);
            sPay[slot] = pay[i];
        }
    }
    __syncthreads();

    // streamout: coalesced 16B stores to this block's private slab
    for (unsigned int i = t; i < total; i += 512)
        payload[(size_t)e0 + i] = sPay[i];

    // packed offset table, coalesced row write
    for (int b = t; b < NBKT; b += 512) {
        unsigned int s = sStart[b];
        unsigned int nxt = (b < NBKT - 1) ? sStart[b + 1] : total;
        off_tab[(size_t)blockIdx.x * NBKT + b] = s | ((nxt - s) << 16);
    }
}

// ---------- per-edge accumulation: 9 scattered LDS atomics -------------------
__device__ __forceinline__ void process_edge(float4 r, float* sC)
{
    float xj = r.z;
    unsigned int w = __float_as_uint(r.w);
    int   rel = (int)((w >> 16) & 63u);
    float p2  = (float)(w & 0xFFFFu) * (1.0f / 65535.0f);

    float v0 = r.x * 4.0f, v1 = r.y * 4.0f, v2 = p2 * 4.0f;
    float i0 = fminf(fmaxf(floorf(v0), 0.0f), 3.0f);
    float i1 = fminf(fmaxf(floorf(v1), 0.0f), 3.0f);
    float i2 = fminf(fmaxf(floorf(v2), 0.0f), 3.0f);
    float f0 = v0 - i0, f1 = v1 - i1, f2 = v2 - i2;
    float g0 = 1.0f - f0, g1 = 1.0f - f1, g2 = 1.0f - f2;
    int k = (int)i0 + 5 * (int)i1 + 25 * (int)i2;        // 0..93

    float w00 = g0 * g1, w10 = f0 * g1, w01 = g0 * f1, w11 = f0 * f1;
    float a2 = xj * g2, b2 = xj * f2;
    float* row = sC + rel * SCS;
    atomicAdd(row + k +  0, w00 * a2);
    atomicAdd(row + k +  1, w10 * a2);
    atomicAdd(row + k +  5, w01 * a2);
    atomicAdd(row + k +  6, w11 * a2);
    atomicAdd(row + k + 25, w00 * b2);
    atomicAdd(row + k + 26, w10 * b2);
    atomicAdd(row + k + 30, w01 * b2);
    atomicAdd(row + k + 31, w11 * b2);
    atomicAdd(row + DEGS, 1.0f);                         // degree
}

// ---------- K2: owner block — edge accumulate + GEMM + h write (NO atomics) --
__global__ __launch_bounds__(512) void owner_kernel(
    const float4* __restrict__ payload,
    const unsigned int* __restrict__ off_tab,   // [nSB][NBKT] packed
    const float* __restrict__ W,        // [125,32]
    const float* __restrict__ x,        // [N,1]
    const float* __restrict__ W_root,   // [32]
    const float* __restrict__ bias,     // [32]
    float4* __restrict__ h4,            // [N*8] = h[N,32] as float4
    int Nn, int nSB)
{
    __shared__ __align__(16) float sC[NPB * SCS];   // 33792 B
    __shared__ unsigned int sEdge[ECAP];            // 12288 B
    __shared__ unsigned int sNe;

    const int t = threadIdx.x;
    const int b = blockIdx.x;
    const int lane = t & 63;

    // zero sC
    for (int i = t; i < NPB * SCS / 4; i += 512)
        *(float4*)&sC[i * 4] = make_float4(0.f, 0.f, 0.f, 0.f);
    if (t == 0) sNe = 0;

    // my fragment (sort block t's slice of bucket b)
    unsigned int cnt = 0, start_g = 0;
    if (t < nSB) {
        unsigned int packed = off_tab[(size_t)t * NBKT + b];
        start_g = (unsigned int)t * SEB + (packed & 0xFFFFu);
        cnt = packed >> 16;
    }
    __syncthreads();

    // wave-level exclusive prefix of cnt -> compact work list offsets
    unsigned int incl = cnt;
    #pragma unroll
    for (int d = 1; d < 64; d <<= 1) {
        unsigned int v = __shfl_up(incl, d, 64);
        if (lane >= d) incl += v;
    }
    unsigned int wtot = __shfl(incl, 63, 64);
    unsigned int wbase = 0;
    if (lane == 63 && wtot > 0) wbase = atomicAdd(&sNe, wtot);
    wbase = __shfl(wbase, 63, 64);
    unsigned int off = wbase + incl - cnt;

    for (unsigned int j = 0; j < cnt; ++j) {
        unsigned int p = off + j;
        if (p < ECAP) sEdge[p] = start_g + j;
        else process_edge(payload[start_g + j], sC);   // statistically unreachable
    }
    __syncthreads();

    // edge phase (R8 form)
    int ne = (int)sNe; if (ne > ECAP) ne = ECAP;
    for (int i = t; i < ne; i += 512)
        process_edge(payload[sEdge[i]], sC);
    __syncthreads();

    // dense GEMM: [64 x 125] @ [125 x 32], 4 channels/thread (R8 rolled form)
    const int node = t & 63;
    const int cg   = t >> 6;                 // wave-uniform channel group 0..7
    const float* crow = sC + node * SCS;
    float4 acc = make_float4(0.f, 0.f, 0.f, 0.f);
    #pragma unroll 8
    for (int k4 = 0; k4 < 31; ++k4) {        // k = 0..123
        float4 r = *(const float4*)&crow[k4 * 4];
        const float* wp = W + (k4 * 4) * F_OUT + cg * 4;
        float4 w0 = *(const float4*)(wp);
        float4 w1 = *(const float4*)(wp + F_OUT);
        float4 w2 = *(const float4*)(wp + 2 * F_OUT);
        float4 w3 = *(const float4*)(wp + 3 * F_OUT);
        acc.x += r.x * w0.x + r.y * w1.x + r.z * w2.x + r.w * w3.x;
        acc.y += r.x * w0.y + r.y * w1.y + r.z * w2.y + r.w * w3.y;
        acc.z += r.x * w0.z + r.y * w1.z + r.z * w2.z + r.w * w3.z;
        acc.w += r.x * w0.w + r.y * w1.w + r.z * w2.w + r.w * w3.w;
    }
    {   // k = 124
        float r = crow[124];
        const float* wp = W + 124 * F_OUT + cg * 4;
        acc.x += r * wp[0]; acc.y += r * wp[1];
        acc.z += r * wp[2]; acc.w += r * wp[3];
    }
    float dg = fmaxf(crow[DEGS], 1.0f);
    int   n  = b * NPB + node;
    float xn = (n < Nn) ? x[n] : 0.0f;
    float4 wr = *(const float4*)(W_root + cg * 4);
    float4 bs = *(const float4*)(bias + cg * 4);
    __syncthreads();                          // all sC reads done

    // epilogue into sC slots 0..31 per node
    if (n < Nn) {
        float h;
        h = acc.x / dg + xn * wr.x + bs.x; h = h > 0.f ? h : expm1f(h); sC[node * SCS + cg * 4 + 0] = h;
        h = acc.y / dg + xn * wr.y + bs.y; h = h > 0.f ? h : expm1f(h); sC[node * SCS + cg * 4 + 1] = h;
        h = acc.z / dg + xn * wr.z + bs.z; h = h > 0.f ? h : expm1f(h); sC[node * SCS + cg * 4 + 2] = h;
        h = acc.w / dg + xn * wr.w + bs.w; h = h > 0.f ? h : expm1f(h); sC[node * SCS + cg * 4 + 3] = h;
    }
    __syncthreads();

    // coalesced h write: h4[n0*8 + item] is fully contiguous across the block
    const int n0 = b * NPB;
    for (int item = t; item < NPB * 8; item += 512) {
        int nr = item >> 3, q = item & 7;
        if (n0 + nr >= Nn) break;
        h4[(size_t)n0 * 8 + item] = *(const float4*)&sC[nr * SCS + q * 4];
    }
}

// ---------- K3: voxel scatter-max (isolated for profiling) -------------------
__global__ __launch_bounds__(256) void voxmax_kernel(
    const float* __restrict__ h,        // [N,32]
    const float* __restrict__ pos,      // [N,3]
    unsigned int* __restrict__ pooled,  // [NUM_VOX,32] encoded
    int Nn)
{
    int gid = blockIdx.x * 256 + threadIdx.x;
    int n = gid >> 5, o = gid & 31;
    if (n >= Nn) return;
    float hv = h[(size_t)n * F_OUT + o];
    int vx = min(max((int)floorf(pos[3 * n + 0] * (float)GRID_DIM), 0), GRID_DIM - 1);
    int vy = min(max((int)floorf(pos[3 * n + 1] * (float)GRID_DIM), 0), GRID_DIM - 1);
    int vz = min(max((int)floorf(pos[3 * n + 2] * (float)GRID_DIM), 0), GRID_DIM - 1);
    int vidx = vx + GRID_DIM * vy + GRID_DIM * GRID_DIM * vz;
    atomicMax(&pooled[(size_t)vidx * F_OUT + o], enc_f32(hv));
}

// ---------- K4: decode, empty voxels -> 0 ------------------------------------
__global__ __launch_bounds__(256) void finalize_kernel(
    const unsigned int* __restrict__ pooled,
    float* __restrict__ out, int M)
{
    int i = blockIdx.x * blockDim.x + threadIdx.x;
    if (i >= M) return;
    unsigned int u = pooled[i];
    out[i] = (u == 0u) ? 0.0f : dec_f32(u);
}

// ============================ launcher =======================================
extern "C" void kernel_launch(void* const* d_in, const int* in_sizes, int n_in,
                              void* d_out, int out_size, void* d_ws, size_t ws_size,
                              hipStream_t stream) {
    const float* x       = (const float*)d_in[0];
    const int*   ei      = (const int*)  d_in[1];
    const float* pseudo  = (const float*)d_in[2];
    const float* pos     = (const float*)d_in[3];
    const float* W       = (const float*)d_in[4];
    const float* W_root  = (const float*)d_in[5];
    const float* bias    = (const float*)d_in[6];
    float* out = (float*)d_out;

    const int E   = in_sizes[1] / 2;
    const int Nn  = in_sizes[0];                  // F_IN == 1, Nn <= 65536
    const int nSB = (E + SEB - 1) / SEB;          // sort blocks (512 here)
    const int nb  = (Nn + NPB - 1) / NPB;         // owner buckets (1024 here)

    // workspace: [pooled 4MB][off_tab 2MB][payload 16.8MB][h 8MB]  ~31.5 MB
    const size_t pooled_b = (size_t)NUM_VOX * F_OUT * 4;
    const size_t off_b    = ((size_t)nSB * NBKT * 4 + 15) & ~(size_t)15;
    const size_t pay_b    = (size_t)nSB * SEB * 16;
    unsigned int* pooled  = (unsigned int*)d_ws;
    unsigned int* off_tab = (unsigned int*)((char*)d_ws + pooled_b);
    float4*       payload = (float4*)((char*)d_ws + pooled_b + off_b);
    float4*       h4      = (float4*)((char*)d_ws + pooled_b + off_b + pay_b);

    hipMemsetAsync(pooled, 0, pooled_b, stream);

    sort_kernel<<<nSB, 512, 0, stream>>>(ei, ei + E, x, pseudo, payload, off_tab, E);
    owner_kernel<<<nb, 512, 0, stream>>>(payload, off_tab, W, x, W_root, bias,
                                         h4, Nn, nSB);
    voxmax_kernel<<<(Nn * F_OUT + 255) / 256, 256, 0, stream>>>(
        (const float*)h4, pos, pooled, Nn);

    const int M = (out_size < NUM_VOX * F_OUT) ? out_size : NUM_VOX * F_OUT;
    finalize_kernel<<<(M + 255) / 256, 256, 0, stream>>>(pooled, out, M);
}